// Round 1
// baseline (812.435 us; speedup 1.0000x reference)
//
#include <hip/hip_runtime.h>
#include <math.h>

// Problem constants (fixed by setup_inputs)
#define NB 2
#define NH 12
#define NW 12
#define NK 3
#define NI 32
#define NO 32
#define NBHW (NB*NH*NW)        // 288 spatial positions
#define NC (NK*NK*NI)          // 288 children per position
#define VPB (NC*NO*16)         // 147456 votes floats per bhw (o-major, a-minor)
#define HR 14
#define WR 14
#define EPSF 1e-7f
#define MINVAR 5e-4f
#define TEMP0 0.0005f          // 0.01*(1-0.95^1), m_step it=0
#define TEMPF 0.00142625f      // 0.01*(1-0.95^3), final m_step

#define CH 8                   // chunks of the child dim
#define CPC (NC/CH)            // 36 children per chunk-unit
#define UNITS (NBHW*CH)        // 2304 work units for votes passes
#define GRID 768               // 3 blocks/CU guaranteed resident
#define UPB (UNITS/GRID)       // 3 units per block (exact)
#define ITERS (CPC/4)          // 9 iters, 4 children per block-iter

// ---- Workspace layout (float offsets) ----
#define DENSE_N (NB*HR*WR*NI)  // 12544
#define BAR_OFF   0            // 16 uints (grid barriers), memset with dense
#define DENSE_OFF 16
#define S1_OFF    (DENSE_OFF + DENSE_N)      // [UNITS*2][512] chunk-half partials
#define S2_OFF    (S1_OFF + UNITS*2*512)
#define SR_OFF    (S2_OFF + UNITS*2*512)     // [UNITS*2]
#define MU_OFF    (SR_OFF + UNITS*2)         // [288][512] stored (a*32+o)
#define W_OFF     (MU_OFF + NBHW*512)        // 0.5/sig, same layout
#define L_OFF     (W_OFF + NBHW*512)         // [288][32] log(aj)-sum log(2pi sig)
#define BM_OFF    (L_OFF + NBHW*32)          // [UNITS] per-unit lognum max
#define LOG_OFF   (BM_OFF + UNITS)           // [288][288][32] lognum
#define DSR_OFF   (LOG_OFF + NBHW*NC*NO)     // [UNITS][32] per-o sumR (final pass)
// D-pass S1/S2 alias the P-pass S1/S2 regions (dead after phase 2a).

__device__ __forceinline__ void gsync(unsigned* bar) {
    __syncthreads();
    if (threadIdx.x == 0) {
        __threadfence();
        __hip_atomic_fetch_add(bar, 1u, __ATOMIC_ACQ_REL, __HIP_MEMORY_SCOPE_AGENT);
        while (__hip_atomic_load(bar, __ATOMIC_ACQUIRE, __HIP_MEMORY_SCOPE_AGENT) < GRID)
            __builtin_amdgcn_s_sleep(1);
        __threadfence();
    }
    __syncthreads();
}

__global__ __launch_bounds__(256, 3) void em_mega(
        const float* __restrict__ votes, const float* __restrict__ acts,
        const float* __restrict__ beta_a, const float* __restrict__ beta_u,
        float* __restrict__ ws, float* __restrict__ out) {
    __shared__ float s_acts[CPC];
    __shared__ float s_mu[512], s_w[512], s_L[32];
    __shared__ float smax[4];
    __shared__ float s_rd[CPC];
    __shared__ float s_ra[CPC*NO];
    __shared__ float sSR[64];
    unsigned* bar = (unsigned*)ws;
    const int bid = blockIdx.x;
    const int t = threadIdx.x;
    const int child_sub = t >> 7;       // which half of the block
    const int rem = t & 127;            // float4 index within a child row

    // ================= P1: m_step 1 partial moments (R uniform = 1/NO) =====
    for (int p = 0; p < UPB; ++p) {
        const int u = bid*UPB + p;
        const int bhw = u >> 3;
        const int cbase = (u & 7)*CPC;
        __syncthreads();
        if (t < CPC) s_acts[t] = acts[bhw*NC + cbase + t] * (1.0f/NO);
        __syncthreads();
        const float4* vb4 = (const float4*)votes + (size_t)bhw*(VPB/4) + (size_t)cbase*128;
        float s1[4] = {0,0,0,0}, s2[4] = {0,0,0,0};
        float sumR = 0.f;
        #pragma unroll 3
        for (int it = 0; it < ITERS; ++it) {
            const int c0 = it*4 + child_sub, c1 = c0 + 2;
            float4 v0 = vb4[(size_t)c0*128 + rem];
            float4 v1 = vb4[(size_t)c1*128 + rem];
            float ra0 = s_acts[c0], ra1 = s_acts[c1];
            float w;
            w = ra0*v0.x; s1[0] += w; s2[0] = fmaf(w, v0.x, s2[0]);
            w = ra0*v0.y; s1[1] += w; s2[1] = fmaf(w, v0.y, s2[1]);
            w = ra0*v0.z; s1[2] += w; s2[2] = fmaf(w, v0.z, s2[2]);
            w = ra0*v0.w; s1[3] += w; s2[3] = fmaf(w, v0.w, s2[3]);
            w = ra1*v1.x; s1[0] += w; s2[0] = fmaf(w, v1.x, s2[0]);
            w = ra1*v1.y; s1[1] += w; s2[1] = fmaf(w, v1.y, s2[1]);
            w = ra1*v1.z; s1[2] += w; s2[2] = fmaf(w, v1.z, s2[2]);
            w = ra1*v1.w; s1[3] += w; s2[3] = fmaf(w, v1.w, s2[3]);
            sumR += ra0 + ra1;
        }
        const int slot = u*2 + child_sub;   // each half stores its own partial
        ((float4*)(ws + S1_OFF))[slot*128 + rem] = make_float4(s1[0],s1[1],s1[2],s1[3]);
        ((float4*)(ws + S2_OFF))[slot*128 + rem] = make_float4(s2[0],s2[1],s2[2],s2[3]);
        if (rem == 0) ws[SR_OFF + slot] = sumR;
    }
    gsync(&bar[0]);

    // ================= P2a: per-bhw finalize (once, not redundantly) =======
    if (bid < NBHW) {
        const int bhw = bid;
        float sumR = 0.f;
        #pragma unroll
        for (int s = 0; s < 16; ++s) sumR += ws[SR_OFF + bhw*16 + s];
        #pragma unroll
        for (int half = 0; half < 2; ++half) {
            const int idx = t + half*256;        // = o*16 + a
            float s1 = 0.f, s2 = 0.f;
            #pragma unroll
            for (int s = 0; s < 16; ++s) {
                s1 += ws[S1_OFF + (size_t)(bhw*16 + s)*512 + idx];
                s2 += ws[S2_OFF + (size_t)(bhw*16 + s)*512 + idx];
            }
            const int o = idx >> 4, a = idx & 15;
            float mu  = s1 / (sumR + EPSF);
            float sig = (s2 - mu*(2.f*s1 - mu*sumR)) / (sumR + EPSF) + MINVAR;
            ws[MU_OFF + bhw*512 + a*32 + o] = mu;
            ws[W_OFF  + bhw*512 + a*32 + o] = 0.5f / sig;
            float cost = (beta_u[o] - 0.5f*logf(sig + EPSF)) * sumR;
            float ps   = logf(6.2831853071795864f * sig);
            #pragma unroll
            for (int d = 1; d < 16; d <<= 1) {
                cost += __shfl_xor(cost, d);
                ps   += __shfl_xor(ps, d);
            }
            if (a == 0) {
                float aj = 1.0f/(1.0f + expf(-TEMP0*(beta_a[o] - cost)));
                ws[L_OFF + bhw*32 + o] = logf(aj) - ps;
            }
        }
    }
    gsync(&bar[1]);

    // ================= P2b: lognum pass over votes ==========================
    for (int p = 0; p < UPB; ++p) {
        const int u = bid*UPB + p;
        const int bhw = u >> 3;
        const int cbase = (u & 7)*CPC;
        __syncthreads();
        s_mu[t]     = ws[MU_OFF + bhw*512 + t];
        s_mu[t+256] = ws[MU_OFF + bhw*512 + t + 256];
        s_w[t]      = ws[W_OFF + bhw*512 + t];
        s_w[t+256]  = ws[W_OFF + bhw*512 + t + 256];
        if (t < 32) s_L[t] = ws[L_OFF + bhw*32 + t];
        __syncthreads();
        const int o = rem >> 2, quad = rem & 3;
        float mur[4], wr[4];
        #pragma unroll
        for (int j = 0; j < 4; ++j) {
            mur[j] = s_mu[(quad*4 + j)*32 + o];
            wr[j]  = s_w [(quad*4 + j)*32 + o];
        }
        const float L = s_L[o];
        const float4* vb4 = (const float4*)votes + (size_t)bhw*(VPB/4) + (size_t)cbase*128;
        float* lp = ws + LOG_OFF + (size_t)(bhw*NC + cbase)*32;
        float tmax = -3.0e38f;
        #pragma unroll 3
        for (int it = 0; it < ITERS; ++it) {
            const int c0 = it*4 + child_sub, c1 = c0 + 2;
            float4 v0 = vb4[(size_t)c0*128 + rem];
            float4 v1 = vb4[(size_t)c1*128 + rem];
            float d, acc0, acc1;
            d = v0.x - mur[0]; acc0 = d*d*wr[0];
            d = v0.y - mur[1]; acc0 = fmaf(d*d, wr[1], acc0);
            d = v0.z - mur[2]; acc0 = fmaf(d*d, wr[2], acc0);
            d = v0.w - mur[3]; acc0 = fmaf(d*d, wr[3], acc0);
            d = v1.x - mur[0]; acc1 = d*d*wr[0];
            d = v1.y - mur[1]; acc1 = fmaf(d*d, wr[1], acc1);
            d = v1.z - mur[2]; acc1 = fmaf(d*d, wr[2], acc1);
            d = v1.w - mur[3]; acc1 = fmaf(d*d, wr[3], acc1);
            acc0 += __shfl_xor(acc0, 1); acc0 += __shfl_xor(acc0, 2);
            acc1 += __shfl_xor(acc1, 1); acc1 += __shfl_xor(acc1, 2);
            float ln0 = L - acc0, ln1 = L - acc1;
            if (quad == 0) { lp[c0*32 + o] = ln0; lp[c1*32 + o] = ln1; }
            tmax = fmaxf(tmax, fmaxf(ln0, ln1));
        }
        #pragma unroll
        for (int d = 1; d < 64; d <<= 1) tmax = fmaxf(tmax, __shfl_xor(tmax, d));
        if ((t & 63) == 0) smax[t >> 6] = tmax;
        __syncthreads();
        if (t == 0)
            ws[BM_OFF + u] = fmaxf(fmaxf(smax[0], smax[1]), fmaxf(smax[2], smax[3]));
    }
    gsync(&bar[2]);

    // ================= P3: global max + exp/sum_o + scatter to dense ========
    float M;
    {
        float m = -3.0e38f;
        for (int i = t; i < UNITS; i += 256) m = fmaxf(m, ws[BM_OFF + i]);
        #pragma unroll
        for (int d = 1; d < 64; d <<= 1) m = fmaxf(m, __shfl_xor(m, d));
        __syncthreads();
        if ((t & 63) == 0) smax[t >> 6] = m;
        __syncthreads();
        M = fmaxf(fmaxf(smax[0], smax[1]), fmaxf(smax[2], smax[3]));
    }
    for (int p = 0; p < UPB; ++p) {
        const int u = bid*UPB + p;
        const int bhw = u >> 3;
        const int cbase = (u & 7)*CPC;
        const int b = bhw / (NH*NW);
        const int remhw = bhw % (NH*NW);
        const int y = remhw / NW, x = remhw % NW;
        const float* lp = ws + LOG_OFF + (size_t)(bhw*NC + cbase)*32;
        const int o = t & 31, cg = t >> 5;
        for (int it = 0; it < 5; ++it) {
            const int c_loc = it*8 + cg;
            const bool act = c_loc < CPC;
            float s = act ? expf(lp[c_loc*32 + o] - M) : 0.f;
            #pragma unroll
            for (int d = 1; d < 32; d <<= 1) s += __shfl_xor(s, d);
            if (act && o == 0) {
                const int c = cbase + c_loc;
                const int i = c & 31, kk = c >> 5;
                const int ky = kk / 3, kx = kk % 3;
                atomicAdd(ws + DENSE_OFF + ((b*HR + y+ky)*WR + (x+kx))*NI + i, s);
            }
        }
    }
    gsync(&bar[3]);

    // ================= P4: final m_step partial moments =====================
    for (int p = 0; p < UPB; ++p) {
        const int u = bid*UPB + p;
        const int bhw = u >> 3;
        const int cbase = (u & 7)*CPC;
        const int b = bhw / (NH*NW);
        const int remhw = bhw % (NH*NW);
        const int y = remhw / NW, x = remhw % NW;
        __syncthreads();
        if (t < CPC) {
            const int c = cbase + t;
            const int i = c & 31, kk = c >> 5;
            const int ky = kk / 3, kx = kk % 3;
            float dn = ws[DENSE_OFF + ((b*HR + y+ky)*WR + (x+kx))*NI + i];
            s_rd[t] = acts[bhw*NC + c] / (dn + EPSF);
        }
        __syncthreads();
        const float* lp = ws + LOG_OFF + (size_t)(bhw*NC + cbase)*32;
        for (int idx = t; idx < CPC*NO; idx += 256)
            s_ra[idx] = s_rd[idx >> 5] * expf(lp[idx] - M);
        __syncthreads();
        const int o = rem >> 2, quad = rem & 3;
        const float4* vb4 = (const float4*)votes + (size_t)bhw*(VPB/4) + (size_t)cbase*128;
        float s1[4] = {0,0,0,0}, s2[4] = {0,0,0,0};
        float sumR = 0.f;
        #pragma unroll 3
        for (int it = 0; it < ITERS; ++it) {
            const int c0 = it*4 + child_sub, c1 = c0 + 2;
            float4 v0 = vb4[(size_t)c0*128 + rem];
            float4 v1 = vb4[(size_t)c1*128 + rem];
            float ra0 = s_ra[c0*32 + o], ra1 = s_ra[c1*32 + o];
            float w;
            w = ra0*v0.x; s1[0] += w; s2[0] = fmaf(w, v0.x, s2[0]);
            w = ra0*v0.y; s1[1] += w; s2[1] = fmaf(w, v0.y, s2[1]);
            w = ra0*v0.z; s1[2] += w; s2[2] = fmaf(w, v0.z, s2[2]);
            w = ra0*v0.w; s1[3] += w; s2[3] = fmaf(w, v0.w, s2[3]);
            w = ra1*v1.x; s1[0] += w; s2[0] = fmaf(w, v1.x, s2[0]);
            w = ra1*v1.y; s1[1] += w; s2[1] = fmaf(w, v1.y, s2[1]);
            w = ra1*v1.z; s1[2] += w; s2[2] = fmaf(w, v1.z, s2[2]);
            w = ra1*v1.w; s1[3] += w; s2[3] = fmaf(w, v1.w, s2[3]);
            sumR += ra0 + ra1;
        }
        const int slot = u*2 + child_sub;
        ((float4*)(ws + S1_OFF))[slot*128 + rem] = make_float4(s1[0],s1[1],s1[2],s1[3]);
        ((float4*)(ws + S2_OFF))[slot*128 + rem] = make_float4(s2[0],s2[1],s2[2],s2[3]);
        if (quad == 0) sSR[child_sub*32 + o] = sumR;   // quads identical
        __syncthreads();
        if (t < 32) ws[DSR_OFF + u*32 + t] = sSR[t] + sSR[32 + t];
    }
    gsync(&bar[4]);

    // ================= P5: reduce chunk slots, write outputs ================
    if (bid < NBHW*2) {
        const int bhw = bid >> 1;
        const int obase = (bid & 1)*16;
        const int a = t & 15;
        const int o = obase + (t >> 4);
        float s1 = 0.f, s2 = 0.f, sumR = 0.f;
        #pragma unroll
        for (int ch = 0; ch < CH; ++ch) {
            const int u = bhw*8 + ch;
            s1 += ws[S1_OFF + (size_t)(u*2  )*512 + obase*16 + t]
                + ws[S1_OFF + (size_t)(u*2+1)*512 + obase*16 + t];
            s2 += ws[S2_OFF + (size_t)(u*2  )*512 + obase*16 + t]
                + ws[S2_OFF + (size_t)(u*2+1)*512 + obase*16 + t];
            sumR += ws[DSR_OFF + u*32 + o];
        }
        float mu  = s1 / (sumR + EPSF);
        float sig = (s2 - mu*(2.f*s1 - mu*sumR)) / (sumR + EPSF) + MINVAR;
        out[bhw*512 + obase*16 + t] = mu;              // poses (b,h,w,o,a,a)
        float cost = (beta_u[o] - 0.5f*logf(sig + EPSF)) * sumR;
        #pragma unroll
        for (int d = 1; d < 16; d <<= 1) cost += __shfl_xor(cost, d);
        if (a == 0) {
            float aj = 1.0f/(1.0f + expf(-TEMPF*(beta_a[o] - cost)));
            out[NBHW*512 + bhw*32 + o] = aj;           // acts (b,h,w,o)
        }
    }
}

extern "C" void kernel_launch(void* const* d_in, const int* in_sizes, int n_in,
                              void* d_out, int out_size, void* d_ws, size_t ws_size,
                              hipStream_t stream) {
    const float* votes  = (const float*)d_in[0];
    const float* acts   = (const float*)d_in[1];
    const float* beta_a = (const float*)d_in[2];
    const float* beta_u = (const float*)d_in[3];
    float* ws  = (float*)d_ws;
    float* out = (float*)d_out;

    // zero grid-barrier counters + dense grid (graph-capturable async memset)
    hipMemsetAsync(d_ws, 0, (size_t)(DENSE_OFF + DENSE_N)*sizeof(float), stream);
    em_mega<<<GRID, 256, 0, stream>>>(votes, acts, beta_a, beta_u, ws, out);
}

// Round 2
// 655.210 us; speedup vs baseline: 1.2400x; 1.2400x over previous
//
#include <hip/hip_runtime.h>
#include <math.h>

// Problem constants (fixed by setup_inputs)
#define NB 2
#define NH 12
#define NW 12
#define NK 3
#define NI 32
#define NO 32
#define NBHW (NB*NH*NW)        // 288 spatial positions
#define NC (NK*NK*NI)          // 288 children per position
#define VPB (NC*NO*16)         // 147456 votes floats per bhw (o-major, a-minor)
#define HR 14
#define WR 14
#define EPSF 1e-7f
#define MINVAR 5e-4f
#define TEMP0 0.0005f          // 0.01*(1-0.95^1), m_step it=0
#define TEMPF 0.00142625f      // 0.01*(1-0.95^3), final m_step

#define CH 8                   // chunks of the child dim
#define CPC (NC/CH)            // 36 children per chunk-unit
#define UNITS (NBHW*CH)        // 2304 work units for votes passes
#define GRID 768               // 3 blocks/CU guaranteed resident
#define UPB (UNITS/GRID)       // 3 units per block (exact)
#define ITERS (CPC/4)          // 9 iters, 4 children per block-iter

// ---- Workspace layout (float offsets) ----
#define DENSE_N (NB*HR*WR*NI)  // 12544
#define BAR_OFF   0            // 16 uints (grid barriers), memset with dense
#define DENSE_OFF 16
#define S1_OFF    (DENSE_OFF + DENSE_N)      // [UNITS*2][512] chunk-half partials
#define S2_OFF    (S1_OFF + UNITS*2*512)
#define SR_OFF    (S2_OFF + UNITS*2*512)     // [UNITS*2]
#define MU_OFF    (SR_OFF + UNITS*2)         // [288][512] stored (a*32+o)
#define W_OFF     (MU_OFF + NBHW*512)        // 0.5/sig, same layout
#define L_OFF     (W_OFF + NBHW*512)         // [288][32] log(aj)-sum log(2pi sig)
#define BM_OFF    (L_OFF + NBHW*32)          // [UNITS] per-unit lognum max
#define LOG_OFF   (BM_OFF + UNITS)           // [288][288][32] lognum
#define DSR_OFF   (LOG_OFF + NBHW*NC*NO)     // [UNITS][32] per-o sumR (final pass)

// One-shot grid barrier. CRITICAL: fences are OUTSIDE the spin loop.
// - RELEASE fetch_add: one wbl2 per block (publishes this phase's ws writes)
// - RELAXED poll: plain sc1 load from the coherence point, NO buffer_inv
// - single ACQUIRE fence on exit: one L2 inv per block per barrier
// Round-1 version polled with ACQUIRE loads -> buffer_inv per poll iteration
// -> continuous full-L2 invalidation across all XCDs -> 650us kernel.
__device__ __forceinline__ void gsync(unsigned* bar) {
    __syncthreads();
    if (threadIdx.x == 0) {
        __hip_atomic_fetch_add(bar, 1u, __ATOMIC_RELEASE, __HIP_MEMORY_SCOPE_AGENT);
        while (__hip_atomic_load(bar, __ATOMIC_RELAXED, __HIP_MEMORY_SCOPE_AGENT) < GRID)
            __builtin_amdgcn_s_sleep(2);
        __builtin_amdgcn_fence(__ATOMIC_ACQUIRE, "agent");
    }
    __syncthreads();
}

__global__ __launch_bounds__(256, 3) void em_mega(
        const float* __restrict__ votes, const float* __restrict__ acts,
        const float* __restrict__ beta_a, const float* __restrict__ beta_u,
        float* __restrict__ ws, float* __restrict__ out) {
    __shared__ float s_acts[CPC];
    __shared__ float s_mu[512], s_w[512], s_L[32];
    __shared__ float smax[4];
    __shared__ float s_rd[CPC];
    __shared__ float s_ra[CPC*NO];
    __shared__ float sSR[64];
    unsigned* bar = (unsigned*)ws;
    const int bid = blockIdx.x;
    const int t = threadIdx.x;
    const int child_sub = t >> 7;       // which half of the block
    const int rem = t & 127;            // float4 index within a child row

    // ================= P1: m_step 1 partial moments (R uniform = 1/NO) =====
    for (int p = 0; p < UPB; ++p) {
        const int u = bid*UPB + p;
        const int bhw = u >> 3;
        const int cbase = (u & 7)*CPC;
        __syncthreads();
        if (t < CPC) s_acts[t] = acts[bhw*NC + cbase + t] * (1.0f/NO);
        __syncthreads();
        const float4* vb4 = (const float4*)votes + (size_t)bhw*(VPB/4) + (size_t)cbase*128;
        float s1[4] = {0,0,0,0}, s2[4] = {0,0,0,0};
        float sumR = 0.f;
        #pragma unroll 3
        for (int it = 0; it < ITERS; ++it) {
            const int c0 = it*4 + child_sub, c1 = c0 + 2;
            float4 v0 = vb4[(size_t)c0*128 + rem];
            float4 v1 = vb4[(size_t)c1*128 + rem];
            float ra0 = s_acts[c0], ra1 = s_acts[c1];
            float w;
            w = ra0*v0.x; s1[0] += w; s2[0] = fmaf(w, v0.x, s2[0]);
            w = ra0*v0.y; s1[1] += w; s2[1] = fmaf(w, v0.y, s2[1]);
            w = ra0*v0.z; s1[2] += w; s2[2] = fmaf(w, v0.z, s2[2]);
            w = ra0*v0.w; s1[3] += w; s2[3] = fmaf(w, v0.w, s2[3]);
            w = ra1*v1.x; s1[0] += w; s2[0] = fmaf(w, v1.x, s2[0]);
            w = ra1*v1.y; s1[1] += w; s2[1] = fmaf(w, v1.y, s2[1]);
            w = ra1*v1.z; s1[2] += w; s2[2] = fmaf(w, v1.z, s2[2]);
            w = ra1*v1.w; s1[3] += w; s2[3] = fmaf(w, v1.w, s2[3]);
            sumR += ra0 + ra1;
        }
        const int slot = u*2 + child_sub;   // each half stores its own partial
        ((float4*)(ws + S1_OFF))[slot*128 + rem] = make_float4(s1[0],s1[1],s1[2],s1[3]);
        ((float4*)(ws + S2_OFF))[slot*128 + rem] = make_float4(s2[0],s2[1],s2[2],s2[3]);
        if (rem == 0) ws[SR_OFF + slot] = sumR;
    }
    gsync(&bar[0]);

    // ================= P2a: per-bhw finalize (once, not redundantly) =======
    if (bid < NBHW) {
        const int bhw = bid;
        float sumR = 0.f;
        #pragma unroll
        for (int s = 0; s < 16; ++s) sumR += ws[SR_OFF + bhw*16 + s];
        #pragma unroll
        for (int half = 0; half < 2; ++half) {
            const int idx = t + half*256;        // = o*16 + a
            float s1 = 0.f, s2 = 0.f;
            #pragma unroll
            for (int s = 0; s < 16; ++s) {
                s1 += ws[S1_OFF + (size_t)(bhw*16 + s)*512 + idx];
                s2 += ws[S2_OFF + (size_t)(bhw*16 + s)*512 + idx];
            }
            const int o = idx >> 4, a = idx & 15;
            float mu  = s1 / (sumR + EPSF);
            float sig = (s2 - mu*(2.f*s1 - mu*sumR)) / (sumR + EPSF) + MINVAR;
            ws[MU_OFF + bhw*512 + a*32 + o] = mu;
            ws[W_OFF  + bhw*512 + a*32 + o] = 0.5f / sig;
            float cost = (beta_u[o] - 0.5f*logf(sig + EPSF)) * sumR;
            float ps   = logf(6.2831853071795864f * sig);
            #pragma unroll
            for (int d = 1; d < 16; d <<= 1) {
                cost += __shfl_xor(cost, d);
                ps   += __shfl_xor(ps, d);
            }
            if (a == 0) {
                float aj = 1.0f/(1.0f + expf(-TEMP0*(beta_a[o] - cost)));
                ws[L_OFF + bhw*32 + o] = logf(aj) - ps;
            }
        }
    }
    gsync(&bar[1]);

    // ================= P2b: lognum pass over votes ==========================
    for (int p = 0; p < UPB; ++p) {
        const int u = bid*UPB + p;
        const int bhw = u >> 3;
        const int cbase = (u & 7)*CPC;
        __syncthreads();
        s_mu[t]     = ws[MU_OFF + bhw*512 + t];
        s_mu[t+256] = ws[MU_OFF + bhw*512 + t + 256];
        s_w[t]      = ws[W_OFF + bhw*512 + t];
        s_w[t+256]  = ws[W_OFF + bhw*512 + t + 256];
        if (t < 32) s_L[t] = ws[L_OFF + bhw*32 + t];
        __syncthreads();
        const int o = rem >> 2, quad = rem & 3;
        float mur[4], wr[4];
        #pragma unroll
        for (int j = 0; j < 4; ++j) {
            mur[j] = s_mu[(quad*4 + j)*32 + o];
            wr[j]  = s_w [(quad*4 + j)*32 + o];
        }
        const float L = s_L[o];
        const float4* vb4 = (const float4*)votes + (size_t)bhw*(VPB/4) + (size_t)cbase*128;
        float* lp = ws + LOG_OFF + (size_t)(bhw*NC + cbase)*32;
        float tmax = -3.0e38f;
        #pragma unroll 3
        for (int it = 0; it < ITERS; ++it) {
            const int c0 = it*4 + child_sub, c1 = c0 + 2;
            float4 v0 = vb4[(size_t)c0*128 + rem];
            float4 v1 = vb4[(size_t)c1*128 + rem];
            float d, acc0, acc1;
            d = v0.x - mur[0]; acc0 = d*d*wr[0];
            d = v0.y - mur[1]; acc0 = fmaf(d*d, wr[1], acc0);
            d = v0.z - mur[2]; acc0 = fmaf(d*d, wr[2], acc0);
            d = v0.w - mur[3]; acc0 = fmaf(d*d, wr[3], acc0);
            d = v1.x - mur[0]; acc1 = d*d*wr[0];
            d = v1.y - mur[1]; acc1 = fmaf(d*d, wr[1], acc1);
            d = v1.z - mur[2]; acc1 = fmaf(d*d, wr[2], acc1);
            d = v1.w - mur[3]; acc1 = fmaf(d*d, wr[3], acc1);
            acc0 += __shfl_xor(acc0, 1); acc0 += __shfl_xor(acc0, 2);
            acc1 += __shfl_xor(acc1, 1); acc1 += __shfl_xor(acc1, 2);
            float ln0 = L - acc0, ln1 = L - acc1;
            if (quad == 0) { lp[c0*32 + o] = ln0; lp[c1*32 + o] = ln1; }
            tmax = fmaxf(tmax, fmaxf(ln0, ln1));
        }
        #pragma unroll
        for (int d = 1; d < 64; d <<= 1) tmax = fmaxf(tmax, __shfl_xor(tmax, d));
        if ((t & 63) == 0) smax[t >> 6] = tmax;
        __syncthreads();
        if (t == 0)
            ws[BM_OFF + u] = fmaxf(fmaxf(smax[0], smax[1]), fmaxf(smax[2], smax[3]));
    }
    gsync(&bar[2]);

    // ================= P3: global max + exp/sum_o + scatter to dense ========
    float M;
    {
        float m = -3.0e38f;
        for (int i = t; i < UNITS; i += 256) m = fmaxf(m, ws[BM_OFF + i]);
        #pragma unroll
        for (int d = 1; d < 64; d <<= 1) m = fmaxf(m, __shfl_xor(m, d));
        __syncthreads();
        if ((t & 63) == 0) smax[t >> 6] = m;
        __syncthreads();
        M = fmaxf(fmaxf(smax[0], smax[1]), fmaxf(smax[2], smax[3]));
    }
    for (int p = 0; p < UPB; ++p) {
        const int u = bid*UPB + p;
        const int bhw = u >> 3;
        const int cbase = (u & 7)*CPC;
        const int b = bhw / (NH*NW);
        const int remhw = bhw % (NH*NW);
        const int y = remhw / NW, x = remhw % NW;
        const float* lp = ws + LOG_OFF + (size_t)(bhw*NC + cbase)*32;
        const int o = t & 31, cg = t >> 5;
        for (int it = 0; it < 5; ++it) {
            const int c_loc = it*8 + cg;
            const bool act = c_loc < CPC;
            float s = act ? expf(lp[c_loc*32 + o] - M) : 0.f;
            #pragma unroll
            for (int d = 1; d < 32; d <<= 1) s += __shfl_xor(s, d);
            if (act && o == 0) {
                const int c = cbase + c_loc;
                const int i = c & 31, kk = c >> 5;
                const int ky = kk / 3, kx = kk % 3;
                atomicAdd(ws + DENSE_OFF + ((b*HR + y+ky)*WR + (x+kx))*NI + i, s);
            }
        }
    }
    gsync(&bar[3]);

    // ================= P4: final m_step partial moments =====================
    for (int p = 0; p < UPB; ++p) {
        const int u = bid*UPB + p;
        const int bhw = u >> 3;
        const int cbase = (u & 7)*CPC;
        const int b = bhw / (NH*NW);
        const int remhw = bhw % (NH*NW);
        const int y = remhw / NW, x = remhw % NW;
        __syncthreads();
        if (t < CPC) {
            const int c = cbase + t;
            const int i = c & 31, kk = c >> 5;
            const int ky = kk / 3, kx = kk % 3;
            float dn = ws[DENSE_OFF + ((b*HR + y+ky)*WR + (x+kx))*NI + i];
            s_rd[t] = acts[bhw*NC + c] / (dn + EPSF);
        }
        __syncthreads();
        const float* lp = ws + LOG_OFF + (size_t)(bhw*NC + cbase)*32;
        for (int idx = t; idx < CPC*NO; idx += 256)
            s_ra[idx] = s_rd[idx >> 5] * expf(lp[idx] - M);
        __syncthreads();
        const int o = rem >> 2, quad = rem & 3;
        const float4* vb4 = (const float4*)votes + (size_t)bhw*(VPB/4) + (size_t)cbase*128;
        float s1[4] = {0,0,0,0}, s2[4] = {0,0,0,0};
        float sumR = 0.f;
        #pragma unroll 3
        for (int it = 0; it < ITERS; ++it) {
            const int c0 = it*4 + child_sub, c1 = c0 + 2;
            float4 v0 = vb4[(size_t)c0*128 + rem];
            float4 v1 = vb4[(size_t)c1*128 + rem];
            float ra0 = s_ra[c0*32 + o], ra1 = s_ra[c1*32 + o];
            float w;
            w = ra0*v0.x; s1[0] += w; s2[0] = fmaf(w, v0.x, s2[0]);
            w = ra0*v0.y; s1[1] += w; s2[1] = fmaf(w, v0.y, s2[1]);
            w = ra0*v0.z; s1[2] += w; s2[2] = fmaf(w, v0.z, s2[2]);
            w = ra0*v0.w; s1[3] += w; s2[3] = fmaf(w, v0.w, s2[3]);
            w = ra1*v1.x; s1[0] += w; s2[0] = fmaf(w, v1.x, s2[0]);
            w = ra1*v1.y; s1[1] += w; s2[1] = fmaf(w, v1.y, s2[1]);
            w = ra1*v1.z; s1[2] += w; s2[2] = fmaf(w, v1.z, s2[2]);
            w = ra1*v1.w; s1[3] += w; s2[3] = fmaf(w, v1.w, s2[3]);
            sumR += ra0 + ra1;
        }
        const int slot = u*2 + child_sub;
        ((float4*)(ws + S1_OFF))[slot*128 + rem] = make_float4(s1[0],s1[1],s1[2],s1[3]);
        ((float4*)(ws + S2_OFF))[slot*128 + rem] = make_float4(s2[0],s2[1],s2[2],s2[3]);
        if (quad == 0) sSR[child_sub*32 + o] = sumR;   // quads identical
        __syncthreads();
        if (t < 32) ws[DSR_OFF + u*32 + t] = sSR[t] + sSR[32 + t];
    }
    gsync(&bar[4]);

    // ================= P5: reduce chunk slots, write outputs ================
    if (bid < NBHW*2) {
        const int bhw = bid >> 1;
        const int obase = (bid & 1)*16;
        const int a = t & 15;
        const int o = obase + (t >> 4);
        float s1 = 0.f, s2 = 0.f, sumR = 0.f;
        #pragma unroll
        for (int ch = 0; ch < CH; ++ch) {
            const int u = bhw*8 + ch;
            s1 += ws[S1_OFF + (size_t)(u*2  )*512 + obase*16 + t]
                + ws[S1_OFF + (size_t)(u*2+1)*512 + obase*16 + t];
            s2 += ws[S2_OFF + (size_t)(u*2  )*512 + obase*16 + t]
                + ws[S2_OFF + (size_t)(u*2+1)*512 + obase*16 + t];
            sumR += ws[DSR_OFF + u*32 + o];
        }
        float mu  = s1 / (sumR + EPSF);
        float sig = (s2 - mu*(2.f*s1 - mu*sumR)) / (sumR + EPSF) + MINVAR;
        out[bhw*512 + obase*16 + t] = mu;              // poses (b,h,w,o,a,a)
        float cost = (beta_u[o] - 0.5f*logf(sig + EPSF)) * sumR;
        #pragma unroll
        for (int d = 1; d < 16; d <<= 1) cost += __shfl_xor(cost, d);
        if (a == 0) {
            float aj = 1.0f/(1.0f + expf(-TEMPF*(beta_a[o] - cost)));
            out[NBHW*512 + bhw*32 + o] = aj;           // acts (b,h,w,o)
        }
    }
}

extern "C" void kernel_launch(void* const* d_in, const int* in_sizes, int n_in,
                              void* d_out, int out_size, void* d_ws, size_t ws_size,
                              hipStream_t stream) {
    const float* votes  = (const float*)d_in[0];
    const float* acts   = (const float*)d_in[1];
    const float* beta_a = (const float*)d_in[2];
    const float* beta_u = (const float*)d_in[3];
    float* ws  = (float*)d_ws;
    float* out = (float*)d_out;

    // zero grid-barrier counters + dense grid (graph-capturable async memset)
    hipMemsetAsync(d_ws, 0, (size_t)(DENSE_OFF + DENSE_N)*sizeof(float), stream);
    em_mega<<<GRID, 256, 0, stream>>>(votes, acts, beta_a, beta_u, ws, out);
}

// Round 3
// 325.090 us; speedup vs baseline: 2.4991x; 2.0155x over previous
//
#include <hip/hip_runtime.h>
#include <math.h>

// Problem constants (fixed by setup_inputs)
#define NB 2
#define NH 12
#define NW 12
#define NK 3
#define NI 32
#define NO 32
#define NBHW (NB*NH*NW)        // 288 spatial positions
#define NC (NK*NK*NI)          // 288 children per position
#define VPB (NC*NO*16)         // 147456 votes floats per bhw (o-major, a-minor)
#define HR 14
#define WR 14
#define EPSF 1e-7f
#define MINVAR 5e-4f
#define TEMP0 0.0005f          // 0.01*(1-0.95^1), m_step it=0
#define TEMPF 0.00142625f      // 0.01*(1-0.95^3), final m_step

// CH=8: 2304 blocks/votes-kernel = 9 blocks/CU -> 8 resident with
// __launch_bounds__(256,8) = 32 waves/CU (vs 18 at CH=4). Rounds 1-2
// showed votes passes are latency-bound and scale ~linearly with
// resident waves (18w:75us/pass vs 12w:110us/pass).
#define CH 8
#define CPC (NC/CH)            // 36 children per unit
#define UNITS (NBHW*CH)        // 2304 work units
#define ITERS (CPC/4)          // 9 iters, 4 children per block-iter

// ---- Workspace layout (float offsets) ----
#define DENSE_N (NB*HR*WR*NI)  // 12544
#define DENSE_OFF 0
#define S1_OFF    (DENSE_OFF + DENSE_N)      // [UNITS*2][512] per-half partials
#define S2_OFF    (S1_OFF + UNITS*2*512)
#define SR_OFF    (S2_OFF + UNITS*2*512)     // [UNITS*2]
#define MU_OFF    (SR_OFF + UNITS*2)         // [288][512] stored (a*32+o)
#define W_OFF     (MU_OFF + NBHW*512)        // 0.5/sig, same layout
#define L_OFF     (W_OFF + NBHW*512)         // [288][32]
#define BM_OFF    (L_OFF + NBHW*32)          // [UNITS] per-unit lognum max
#define LOG_OFF   (BM_OFF + UNITS)           // [288][288][32] lognum
#define DSR_OFF   (LOG_OFF + NBHW*NC*NO)     // [UNITS][32] per-o sumR

// ================= kA: m_step 1 partial moments (R uniform = 1/NO) =========
// grid = UNITS. Also zeroes the dense grid (consumed by kC/kD).
__global__ __launch_bounds__(256, 8) void kA(const float* __restrict__ votes,
        const float* __restrict__ acts, float* __restrict__ ws) {
    __shared__ float s_acts[CPC];
    const int bid = blockIdx.x;
    const int t = threadIdx.x;
    {   // fold dense-grid zeroing into the first kernel
        const int idx = bid*256 + t;
        if (idx < DENSE_N) ws[DENSE_OFF + idx] = 0.f;
    }
    const int u = bid;
    const int bhw = u >> 3;
    const int cbase = (u & 7)*CPC;
    if (t < CPC) s_acts[t] = acts[bhw*NC + cbase + t] * (1.0f/NO);
    __syncthreads();
    const int child_sub = t >> 7;
    const int rem = t & 127;
    const float4* vb4 = (const float4*)votes + (size_t)bhw*(VPB/4) + (size_t)cbase*128;
    float s1[4] = {0,0,0,0}, s2[4] = {0,0,0,0};
    float sumR = 0.f;
    #pragma unroll 3
    for (int it = 0; it < ITERS; ++it) {
        const int c0 = it*4 + child_sub, c1 = c0 + 2;
        float4 v0 = vb4[(size_t)c0*128 + rem];
        float4 v1 = vb4[(size_t)c1*128 + rem];
        float ra0 = s_acts[c0], ra1 = s_acts[c1];
        float w;
        w = ra0*v0.x; s1[0] += w; s2[0] = fmaf(w, v0.x, s2[0]);
        w = ra0*v0.y; s1[1] += w; s2[1] = fmaf(w, v0.y, s2[1]);
        w = ra0*v0.z; s1[2] += w; s2[2] = fmaf(w, v0.z, s2[2]);
        w = ra0*v0.w; s1[3] += w; s2[3] = fmaf(w, v0.w, s2[3]);
        w = ra1*v1.x; s1[0] += w; s2[0] = fmaf(w, v1.x, s2[0]);
        w = ra1*v1.y; s1[1] += w; s2[1] = fmaf(w, v1.y, s2[1]);
        w = ra1*v1.z; s1[2] += w; s2[2] = fmaf(w, v1.z, s2[2]);
        w = ra1*v1.w; s1[3] += w; s2[3] = fmaf(w, v1.w, s2[3]);
        sumR += ra0 + ra1;
    }
    const int slot = u*2 + child_sub;      // each half stores its own partial
    ((float4*)(ws + S1_OFF))[slot*128 + rem] = make_float4(s1[0],s1[1],s1[2],s1[3]);
    ((float4*)(ws + S2_OFF))[slot*128 + rem] = make_float4(s2[0],s2[1],s2[2],s2[3]);
    if (rem == 0) ws[SR_OFF + slot] = sumR;
}

// ================= kB0: per-bhw finalize (once per bhw) =====================
// grid = NBHW, block = 256.
__global__ __launch_bounds__(256) void kB0(const float* __restrict__ beta_a,
        const float* __restrict__ beta_u, float* __restrict__ ws) {
    const int bhw = blockIdx.x;
    const int t = threadIdx.x;
    float sumR = 0.f;
    #pragma unroll
    for (int s = 0; s < 16; ++s) sumR += ws[SR_OFF + bhw*16 + s];
    #pragma unroll
    for (int half = 0; half < 2; ++half) {
        const int idx = t + half*256;        // = o*16 + a
        float s1 = 0.f, s2 = 0.f;
        #pragma unroll
        for (int s = 0; s < 16; ++s) {
            s1 += ws[S1_OFF + (size_t)(bhw*16 + s)*512 + idx];
            s2 += ws[S2_OFF + (size_t)(bhw*16 + s)*512 + idx];
        }
        const int o = idx >> 4, a = idx & 15;
        float mu  = s1 / (sumR + EPSF);
        float sig = (s2 - mu*(2.f*s1 - mu*sumR)) / (sumR + EPSF) + MINVAR;
        ws[MU_OFF + bhw*512 + a*32 + o] = mu;
        ws[W_OFF  + bhw*512 + a*32 + o] = 0.5f / sig;
        float cost = (beta_u[o] - 0.5f*logf(sig + EPSF)) * sumR;
        float ps   = logf(6.2831853071795864f * sig);
        #pragma unroll
        for (int d = 1; d < 16; d <<= 1) {
            cost += __shfl_xor(cost, d);
            ps   += __shfl_xor(ps, d);
        }
        if (a == 0) {
            float aj = 1.0f/(1.0f + expf(-TEMP0*(beta_a[o] - cost)));
            ws[L_OFF + bhw*32 + o] = logf(aj) - ps;
        }
    }
}

// ================= kB: lognum pass over votes ===============================
// grid = UNITS.
__global__ __launch_bounds__(256, 8) void kB(const float* __restrict__ votes,
        float* __restrict__ ws) {
    __shared__ float s_mu[512], s_w[512], s_L[32], smax[4];
    const int u = blockIdx.x;
    const int bhw = u >> 3;
    const int cbase = (u & 7)*CPC;
    const int t = threadIdx.x;
    const int child_sub = t >> 7;
    const int rem = t & 127;
    s_mu[t]     = ws[MU_OFF + bhw*512 + t];
    s_mu[t+256] = ws[MU_OFF + bhw*512 + t + 256];
    s_w[t]      = ws[W_OFF + bhw*512 + t];
    s_w[t+256]  = ws[W_OFF + bhw*512 + t + 256];
    if (t < 32) s_L[t] = ws[L_OFF + bhw*32 + t];
    __syncthreads();
    const int o = rem >> 2, quad = rem & 3;
    float mur[4], wr[4];
    #pragma unroll
    for (int j = 0; j < 4; ++j) {
        mur[j] = s_mu[(quad*4 + j)*32 + o];
        wr[j]  = s_w [(quad*4 + j)*32 + o];
    }
    const float L = s_L[o];
    const float4* vb4 = (const float4*)votes + (size_t)bhw*(VPB/4) + (size_t)cbase*128;
    float* lp = ws + LOG_OFF + (size_t)(bhw*NC + cbase)*32;
    float tmax = -3.0e38f;
    #pragma unroll 3
    for (int it = 0; it < ITERS; ++it) {
        const int c0 = it*4 + child_sub, c1 = c0 + 2;
        float4 v0 = vb4[(size_t)c0*128 + rem];
        float4 v1 = vb4[(size_t)c1*128 + rem];
        float d, acc0, acc1;
        d = v0.x - mur[0]; acc0 = d*d*wr[0];
        d = v0.y - mur[1]; acc0 = fmaf(d*d, wr[1], acc0);
        d = v0.z - mur[2]; acc0 = fmaf(d*d, wr[2], acc0);
        d = v0.w - mur[3]; acc0 = fmaf(d*d, wr[3], acc0);
        d = v1.x - mur[0]; acc1 = d*d*wr[0];
        d = v1.y - mur[1]; acc1 = fmaf(d*d, wr[1], acc1);
        d = v1.z - mur[2]; acc1 = fmaf(d*d, wr[2], acc1);
        d = v1.w - mur[3]; acc1 = fmaf(d*d, wr[3], acc1);
        acc0 += __shfl_xor(acc0, 1); acc0 += __shfl_xor(acc0, 2);
        acc1 += __shfl_xor(acc1, 1); acc1 += __shfl_xor(acc1, 2);
        float ln0 = L - acc0, ln1 = L - acc1;
        if (quad == 0) { lp[c0*32 + o] = ln0; lp[c1*32 + o] = ln1; }
        tmax = fmaxf(tmax, fmaxf(ln0, ln1));
    }
    #pragma unroll
    for (int d = 1; d < 64; d <<= 1) tmax = fmaxf(tmax, __shfl_xor(tmax, d));
    if ((t & 63) == 0) smax[t >> 6] = tmax;
    __syncthreads();
    if (t == 0)
        ws[BM_OFF + u] = fmaxf(fmaxf(smax[0], smax[1]), fmaxf(smax[2], smax[3]));
}

// ================= kC: global max + exp/sum_o + scatter to dense ============
// grid = UNITS.
__global__ __launch_bounds__(256, 8) void kC(float* __restrict__ ws) {
    __shared__ float smax[4];
    const int u = blockIdx.x;
    const int bhw = u >> 3;
    const int cbase = (u & 7)*CPC;
    const int t = threadIdx.x;
    float m = -3.0e38f;
    for (int i = t; i < UNITS; i += 256) m = fmaxf(m, ws[BM_OFF + i]);
    #pragma unroll
    for (int d = 1; d < 64; d <<= 1) m = fmaxf(m, __shfl_xor(m, d));
    if ((t & 63) == 0) smax[t >> 6] = m;
    __syncthreads();
    const float M = fmaxf(fmaxf(smax[0], smax[1]), fmaxf(smax[2], smax[3]));
    const int b = bhw / (NH*NW);
    const int remhw = bhw % (NH*NW);
    const int y = remhw / NW, x = remhw % NW;
    const float* lp = ws + LOG_OFF + (size_t)(bhw*NC + cbase)*32;
    const int o = t & 31, cg = t >> 5;
    for (int it = 0; it < 5; ++it) {
        const int c_loc = it*8 + cg;
        const bool act = c_loc < CPC;
        float s = act ? expf(lp[c_loc*32 + o] - M) : 0.f;
        #pragma unroll
        for (int d = 1; d < 32; d <<= 1) s += __shfl_xor(s, d);
        if (act && o == 0) {
            const int c = cbase + c_loc;
            const int i = c & 31, kk = c >> 5;
            const int ky = kk / 3, kx = kk % 3;
            atomicAdd(ws + DENSE_OFF + ((b*HR + y+ky)*WR + (x+kx))*NI + i, s);
        }
    }
}

// ================= kD: final m_step partial moments =========================
// grid = UNITS.
__global__ __launch_bounds__(256, 8) void kD(const float* __restrict__ votes,
        const float* __restrict__ acts, float* __restrict__ ws) {
    __shared__ float s_rd[CPC];
    __shared__ float s_ra[CPC*NO];
    __shared__ float smax[4];
    __shared__ float sSR[64];
    const int u = blockIdx.x;
    const int bhw = u >> 3;
    const int cbase = (u & 7)*CPC;
    const int t = threadIdx.x;
    const int b = bhw / (NH*NW);
    const int remhw = bhw % (NH*NW);
    const int y = remhw / NW, x = remhw % NW;
    float m = -3.0e38f;
    for (int i = t; i < UNITS; i += 256) m = fmaxf(m, ws[BM_OFF + i]);
    #pragma unroll
    for (int d = 1; d < 64; d <<= 1) m = fmaxf(m, __shfl_xor(m, d));
    if ((t & 63) == 0) smax[t >> 6] = m;
    if (t < CPC) {
        const int c = cbase + t;
        const int i = c & 31, kk = c >> 5;
        const int ky = kk / 3, kx = kk % 3;
        float dn = ws[DENSE_OFF + ((b*HR + y+ky)*WR + (x+kx))*NI + i];
        s_rd[t] = acts[bhw*NC + c] / (dn + EPSF);
    }
    __syncthreads();
    const float M = fmaxf(fmaxf(smax[0], smax[1]), fmaxf(smax[2], smax[3]));
    const float* lp = ws + LOG_OFF + (size_t)(bhw*NC + cbase)*32;
    for (int idx = t; idx < CPC*NO; idx += 256)
        s_ra[idx] = s_rd[idx >> 5] * expf(lp[idx] - M);
    __syncthreads();
    const int child_sub = t >> 7;
    const int rem = t & 127;
    const int o = rem >> 2, quad = rem & 3;
    const float4* vb4 = (const float4*)votes + (size_t)bhw*(VPB/4) + (size_t)cbase*128;
    float s1[4] = {0,0,0,0}, s2[4] = {0,0,0,0};
    float sumR = 0.f;
    #pragma unroll 3
    for (int it = 0; it < ITERS; ++it) {
        const int c0 = it*4 + child_sub, c1 = c0 + 2;
        float4 v0 = vb4[(size_t)c0*128 + rem];
        float4 v1 = vb4[(size_t)c1*128 + rem];
        float ra0 = s_ra[c0*32 + o], ra1 = s_ra[c1*32 + o];
        float w;
        w = ra0*v0.x; s1[0] += w; s2[0] = fmaf(w, v0.x, s2[0]);
        w = ra0*v0.y; s1[1] += w; s2[1] = fmaf(w, v0.y, s2[1]);
        w = ra0*v0.z; s1[2] += w; s2[2] = fmaf(w, v0.z, s2[2]);
        w = ra0*v0.w; s1[3] += w; s2[3] = fmaf(w, v0.w, s2[3]);
        w = ra1*v1.x; s1[0] += w; s2[0] = fmaf(w, v1.x, s2[0]);
        w = ra1*v1.y; s1[1] += w; s2[1] = fmaf(w, v1.y, s2[1]);
        w = ra1*v1.z; s1[2] += w; s2[2] = fmaf(w, v1.z, s2[2]);
        w = ra1*v1.w; s1[3] += w; s2[3] = fmaf(w, v1.w, s2[3]);
        sumR += ra0 + ra1;
    }
    const int slot = u*2 + child_sub;
    ((float4*)(ws + S1_OFF))[slot*128 + rem] = make_float4(s1[0],s1[1],s1[2],s1[3]);
    ((float4*)(ws + S2_OFF))[slot*128 + rem] = make_float4(s2[0],s2[1],s2[2],s2[3]);
    if (quad == 0) sSR[child_sub*32 + o] = sumR;   // quads identical
    __syncthreads();
    if (t < 32) ws[DSR_OFF + u*32 + t] = sSR[t] + sSR[32 + t];
}

// ================= kD2: reduce chunk slots, write outputs ===================
// grid = NBHW*2, block = 256, t = (o_loc<<4)|a
__global__ __launch_bounds__(256) void kD2(const float* __restrict__ beta_a,
        const float* __restrict__ beta_u, const float* __restrict__ ws,
        float* __restrict__ out) {
    const int bid = blockIdx.x;
    const int bhw = bid >> 1;
    const int obase = (bid & 1)*16;
    const int t = threadIdx.x;
    const int a = t & 15;
    const int o = obase + (t >> 4);
    float s1 = 0.f, s2 = 0.f, sumR = 0.f;
    #pragma unroll
    for (int ch = 0; ch < CH; ++ch) {
        const int u = bhw*8 + ch;
        s1 += ws[S1_OFF + (size_t)(u*2  )*512 + obase*16 + t]
            + ws[S1_OFF + (size_t)(u*2+1)*512 + obase*16 + t];
        s2 += ws[S2_OFF + (size_t)(u*2  )*512 + obase*16 + t]
            + ws[S2_OFF + (size_t)(u*2+1)*512 + obase*16 + t];
        sumR += ws[DSR_OFF + u*32 + o];
    }
    float mu  = s1 / (sumR + EPSF);
    float sig = (s2 - mu*(2.f*s1 - mu*sumR)) / (sumR + EPSF) + MINVAR;
    out[bhw*512 + obase*16 + t] = mu;              // poses (b,h,w,o,a,a)
    float cost = (beta_u[o] - 0.5f*logf(sig + EPSF)) * sumR;
    #pragma unroll
    for (int d = 1; d < 16; d <<= 1) cost += __shfl_xor(cost, d);
    if (a == 0) {
        float aj = 1.0f/(1.0f + expf(-TEMPF*(beta_a[o] - cost)));
        out[NBHW*512 + bhw*32 + o] = aj;           // acts (b,h,w,o)
    }
}

extern "C" void kernel_launch(void* const* d_in, const int* in_sizes, int n_in,
                              void* d_out, int out_size, void* d_ws, size_t ws_size,
                              hipStream_t stream) {
    const float* votes  = (const float*)d_in[0];
    const float* acts   = (const float*)d_in[1];
    const float* beta_a = (const float*)d_in[2];
    const float* beta_u = (const float*)d_in[3];
    float* ws  = (float*)d_ws;
    float* out = (float*)d_out;

    kA <<<UNITS,  256, 0, stream>>>(votes, acts, ws);
    kB0<<<NBHW,   256, 0, stream>>>(beta_a, beta_u, ws);
    kB <<<UNITS,  256, 0, stream>>>(votes, ws);
    kC <<<UNITS,  256, 0, stream>>>(ws);
    kD <<<UNITS,  256, 0, stream>>>(votes, acts, ws);
    kD2<<<NBHW*2, 256, 0, stream>>>(beta_a, beta_u, ws, out);
}